// Round 3
// baseline (1016.655 us; speedup 1.0000x reference)
//
#include <hip/hip_runtime.h>

// N=64, D=128, EMB=64, OUTG=64, A=512, B=256, G=8
// group_mask[i,j] = (j//2 == i).
//
// Mega-kernel k_f: per block = 128 rows (2 consecutive (b,g) pairs, same b).
//   stage emb_s[b] + wadj(2 g's) -> aggr fp32 -> split-pack u32 [hi|lo] LDS A0
//   per cc (4 x 128-col chunks of h0):
//     layer0 MFMA K=128 (ks0,1: aggr from LDS; ks2,3: embA frags from global)
//     epilogue +fb0/leaky/split-pack -> h0chunk LDS (XOR-swizzled granules)
//     layer1 partial MFMA (K-chunk 128) accumulating acc1[4][8]
//   epilogue: +fb1/leaky -> 4x 32-row quarters through LDS -> layer2 (2 cols/row)
// fp16-split x3 MFMA: a = a_hi + a_lo; a*b ~= AhBh + AhBl + AlBh (fp32 acc).

typedef _Float16 half8 __attribute__((ext_vector_type(8)));
typedef float    f32x4 __attribute__((ext_vector_type(4)));
typedef uint32_t u32x4 __attribute__((ext_vector_type(4)));

#define MFMA16(a, b, c) __builtin_amdgcn_mfma_f32_16x16x32_f16(a, b, c, 0, 0, 0)

__device__ __forceinline__ float leaky(float v) { return v >= 0.f ? v : 0.01f * v; }

__device__ __forceinline__ uint32_t packsplit(float v) {
    _Float16 hi = (_Float16)v;
    _Float16 lo = (_Float16)(v - (float)hi);
    union { _Float16 f; unsigned short u; } a, c;
    a.f = hi; c.f = lo;
    return (uint32_t)a.u | ((uint32_t)c.u << 16);
}

__device__ __forceinline__ void unpackA(u32x4 w0, u32x4 w1, half8& Ah, half8& Al) {
    union { u32x4 u; half8 h; } ah, al;
    ah.u[0] = (w0[0] & 0xffffu) | (w0[1] << 16);
    ah.u[1] = (w0[2] & 0xffffu) | (w0[3] << 16);
    ah.u[2] = (w1[0] & 0xffffu) | (w1[1] << 16);
    ah.u[3] = (w1[2] & 0xffffu) | (w1[3] << 16);
    al.u[0] = (w0[0] >> 16) | (w0[1] & 0xffff0000u);
    al.u[1] = (w0[2] >> 16) | (w0[3] & 0xffff0000u);
    al.u[2] = (w1[0] >> 16) | (w1[1] & 0xffff0000u);
    al.u[3] = (w1[2] >> 16) | (w1[3] & 0xffff0000u);
    Ah = ah.h; Al = al.h;
}

// ---------------- prep kernels ----------------

__global__ void k_base(const float* __restrict__ emb,
                       const float* __restrict__ gw0, const float* __restrict__ gb0,
                       const float* __restrict__ fw0, const float* __restrict__ fb0,
                       float* __restrict__ base_g, float* __restrict__ base_f)
{
    int blk = blockIdx.x;            // 256 blocks
    int n     = blk >> 2;
    int half  = (blk >> 1) & 1;
    int which = blk & 1;
    int c = half * 256 + threadIdx.x;
    const float* W    = which ? fw0 : gw0;
    const float* bias = which ? fb0 : gb0;
    float* dst        = which ? base_f : base_g;
    int off           = which ? 64 : 128;
    const float* e = emb + n * 64;
    float acc = bias[c];
    #pragma unroll 8
    for (int k = 0; k < 64; ++k)
        acc = fmaf(e[k], W[(off + k) * 512 + c], acc);
    dst[n * 512 + c] = acc;
}

__global__ void k_w2t(const float* __restrict__ fw2, float* __restrict__ w2T)
{
    int tid = blockIdx.x * 256 + threadIdx.x;   // grid 256 -> 65536
    int c = tid >> 9, a = tid & 511;
    w2T[tid] = fw2[a * 128 + c];
}

// Split fw1 (512x512), fw0 (rows 0..127), and embA (A-frag of embeddings)
// into f16 hi/lo fragment-linear layouts.
__global__ void k_splitw(const float* __restrict__ fw0, const float* __restrict__ fw1,
                         const float* __restrict__ emb,
                         _Float16* __restrict__ fw0h, _Float16* __restrict__ fw0l,
                         _Float16* __restrict__ fw1h, _Float16* __restrict__ fw1l,
                         _Float16* __restrict__ embAh, _Float16* __restrict__ embAl)
{
    int tid = blockIdx.x * 256 + threadIdx.x;
    if (blockIdx.x < 128) {                       // fw1: 16 ksteps x 32 nt
        int l = tid & 63, grp = tid >> 6;
        int kstep = grp >> 5, nt = grp & 31;
        #pragma unroll
        for (int j = 0; j < 8; ++j) {
            int k = kstep * 32 + (l >> 4) * 8 + j;
            int n = nt * 16 + (l & 15);
            float v = fw1[k * 512 + n];
            _Float16 h = (_Float16)v;
            fw1h[tid * 8 + j] = h;
            fw1l[tid * 8 + j] = (_Float16)(v - (float)h);
        }
    } else if (blockIdx.x < 160) {                // fw0 full 128 rows: 4 ksteps x 32 nt
        int t2 = tid - 32768;
        int l = t2 & 63, grp = t2 >> 6;
        int ks = grp >> 5, nt = grp & 31;
        #pragma unroll
        for (int j = 0; j < 8; ++j) {
            int k = ks * 32 + (l >> 4) * 8 + j;
            int n = nt * 16 + (l & 15);
            float v = fw0[k * 512 + n];
            _Float16 h = (_Float16)v;
            fw0h[t2 * 8 + j] = h;
            fw0l[t2 * 8 + j] = (_Float16)(v - (float)h);
        }
    } else {                                      // embA: 4 mt x 2 ks2
        int t3 = tid - 40960;
        int l = t3 & 63, grp = t3 >> 6;
        int mt = grp >> 1, ks2 = grp & 1;
        #pragma unroll
        for (int j = 0; j < 8; ++j) {
            int m  = mt * 16 + (l & 15);
            int ke = ks2 * 32 + (l >> 4) * 8 + j;
            float v = emb[m * 64 + ke];
            _Float16 h = (_Float16)v;
            embAh[t3 * 8 + j] = h;
            embAl[t3 * 8 + j] = (_Float16)(v - (float)h);
        }
    }
}

// ---------------- g-MLP (unchanged, verified) ----------------

template <int KLEN, int LDSSTRIDE>
__device__ __forceinline__ void gemm16x2(const float* __restrict__ W,
                                         const float* sh, int c0, int c1,
                                         float (&acc0)[16], float (&acc1)[16])
{
    for (int k = 0; k < KLEN; k += 4) {
        float wa0 = W[(k + 0) * 512 + c0], wb0 = W[(k + 0) * 512 + c1];
        float wa1 = W[(k + 1) * 512 + c0], wb1 = W[(k + 1) * 512 + c1];
        float wa2 = W[(k + 2) * 512 + c0], wb2 = W[(k + 2) * 512 + c1];
        float wa3 = W[(k + 3) * 512 + c0], wb3 = W[(k + 3) * 512 + c1];
        #pragma unroll
        for (int i = 0; i < 16; ++i) {
            float4 h = *reinterpret_cast<const float4*>(&sh[i * LDSSTRIDE + k]);
            acc0[i] = fmaf(h.x, wa0, acc0[i]); acc1[i] = fmaf(h.x, wb0, acc1[i]);
            acc0[i] = fmaf(h.y, wa1, acc0[i]); acc1[i] = fmaf(h.y, wb1, acc1[i]);
            acc0[i] = fmaf(h.z, wa2, acc0[i]); acc1[i] = fmaf(h.z, wb2, acc1[i]);
            acc0[i] = fmaf(h.w, wa3, acc0[i]); acc1[i] = fmaf(h.w, wb3, acc1[i]);
        }
    }
}

__global__ __launch_bounds__(256, 4) void k_embs(
    const float* __restrict__ samples, const float* __restrict__ gw0,
    const float* __restrict__ gw1, const float* __restrict__ gb1,
    const float* __restrict__ gw2, const float* __restrict__ gb2,
    const float* __restrict__ base_g, float* __restrict__ emb_s)
{
    __shared__ __align__(16) float sh[16 * 512];
    const int t  = threadIdx.x;
    const int r0 = blockIdx.x * 16;
    const int b  = r0 >> 6;
    const int c0 = t, c1 = t + 256;

    #pragma unroll
    for (int i = 0; i < 16; ++i) {
        int n = (r0 + i) & 63;
        float s0 = samples[b * 128 + 2 * n];
        float s1 = samples[b * 128 + 2 * n + 1];
        const float* w0a = gw0 + (2 * n) * 512;
        const float* w0b = gw0 + (2 * n + 1) * 512;
        const float* bg  = base_g + n * 512;
        float v0 = fmaf(s0, w0a[c0], fmaf(s1, w0b[c0], bg[c0]));
        float v1 = fmaf(s0, w0a[c1], fmaf(s1, w0b[c1], bg[c1]));
        sh[i * 512 + c0] = leaky(v0);
        sh[i * 512 + c1] = leaky(v1);
    }
    __syncthreads();

    float acc0[16], acc1[16];
    {
        float bb0 = gb1[c0], bb1 = gb1[c1];
        #pragma unroll
        for (int i = 0; i < 16; ++i) { acc0[i] = bb0; acc1[i] = bb1; }
    }
    gemm16x2<512, 512>(gw1, sh, c0, c1, acc0, acc1);
    __syncthreads();
    #pragma unroll
    for (int i = 0; i < 16; ++i) {
        sh[i * 512 + c0] = leaky(acc0[i]);
        sh[i * 512 + c1] = leaky(acc1[i]);
    }
    __syncthreads();

    int i  = t >> 4;
    int kb = (t & 15) * 4;
    float4 o = *reinterpret_cast<const float4*>(&gb2[kb]);
    for (int a = 0; a < 512; ++a) {
        float  h  = sh[i * 512 + a];
        float4 wv = *reinterpret_cast<const float4*>(&gw2[a * 64 + kb]);
        o.x = fmaf(h, wv.x, o.x); o.y = fmaf(h, wv.y, o.y);
        o.z = fmaf(h, wv.z, o.z); o.w = fmaf(h, wv.w, o.w);
    }
    *reinterpret_cast<float4*>(&emb_s[(r0 + i) * 64 + kb]) = o;
}

// ---------------- fused f-MLP mega-kernel ----------------
// LDS map (96 KB):
//   [0,32K)    A0: packed u32 [128 rows][64 k], swizzled (aggr split)
//   [32K,48K)  s_emb fp32 64x64           (prologue only)
//   [48K,80K)  s_wadj fp32 2x64x64        (prologue only)
//   [32K,96K)  h0chunk packed u32 [128][128], swizzled (main loop)
//   [0,66560)  h1buf fp32 [32][520]       (layer2 epilogue)

__global__ __launch_bounds__(512, 2) void k_f(
    const float* __restrict__ graphs, const float* __restrict__ w,
    const float* __restrict__ emb_s,
    const float* __restrict__ fb0, const float* __restrict__ fb1,
    const float* __restrict__ w2T, const float* __restrict__ fb2,
    const _Float16* __restrict__ fw0h, const _Float16* __restrict__ fw0l,
    const _Float16* __restrict__ fw1h, const _Float16* __restrict__ fw1l,
    const _Float16* __restrict__ embAh, const _Float16* __restrict__ embAl,
    float* __restrict__ out)
{
    __shared__ __align__(16) unsigned char smem[98304];
    const int t  = threadIdx.x;
    const int l  = t & 63;
    const int wv = t >> 6, wm = wv >> 2, wn = wv & 3;
    const int tile = blockIdx.x;     // 1024 tiles of 128 rows
    const int b  = tile >> 2;
    const int g0 = (tile & 3) * 2;   // g pair {g0, g0+1}

    // --- prologue: stage emb_s[b] and wadj(2 g's) ---
    {
        float* se = (float*)(smem + 32768);
        float* sw = (float*)(smem + 49152);
        const float* eb = emb_s + b * 4096;
        *(float4*)(se + t * 8)     = *(const float4*)(eb + t * 8);
        *(float4*)(se + t * 8 + 4) = *(const float4*)(eb + t * 8 + 4);
        #pragma unroll
        for (int it = 0; it < 4; ++it) {
            int idx = (it * 512 + t) * 4;
            int gg = idx >> 12, rem = idx & 4095;
            float4 gr = *(const float4*)(graphs + (g0 + gg) * 4096 + rem);
            float4 ww = *(const float4*)(w + rem);
            float4 m2;
            m2.x = gr.x * ww.x; m2.y = gr.y * ww.y;
            m2.z = gr.z * ww.z; m2.w = gr.w * ww.w;
            *(float4*)(sw + idx) = m2;
        }
    }
    __syncthreads();

    // --- aggr[m][k] (fp32) -> A0 packed u32, swizzled ---
    {
        const float* se = (const float*)(smem + 32768);
        const float* sw = (const float*)(smem + 49152);
        int m = t >> 2, k0 = (t & 3) * 16;
        int gg = m >> 6, node = m & 63;
        float acc[16];
        #pragma unroll
        for (int q = 0; q < 16; ++q) acc[q] = 0.f;
        for (int j = 0; j < 64; ++j) {
            float wc = sw[gg * 4096 + j * 64 + node];
            const float* er = se + j * 64 + k0;
            #pragma unroll
            for (int q = 0; q < 4; ++q) {
                float4 e4 = *(const float4*)(er + q * 4);
                acc[q*4+0] = fmaf(e4.x, wc, acc[q*4+0]);
                acc[q*4+1] = fmaf(e4.y, wc, acc[q*4+1]);
                acc[q*4+2] = fmaf(e4.z, wc, acc[q*4+2]);
                acc[q*4+3] = fmaf(e4.w, wc, acc[q*4+3]);
            }
        }
        #pragma unroll
        for (int q = 0; q < 4; ++q) {
            u32x4 pk;
            #pragma unroll
            for (int e = 0; e < 4; ++e) pk[e] = packsplit(acc[q * 4 + e]);
            int gran = (k0 >> 2) + q;            // 0..15
            *(u32x4*)(smem + m * 256 + ((gran ^ (m & 7)) << 4)) = pk;
        }
    }
    __syncthreads();

    f32x4 zero4 = {0.f, 0.f, 0.f, 0.f};
    f32x4 acc1[4][8];
    #pragma unroll
    for (int mt = 0; mt < 4; ++mt)
        #pragma unroll
        for (int nt = 0; nt < 8; ++nt) acc1[mt][nt] = zero4;

    for (int cc = 0; cc < 4; ++cc) {
        // layer0: h0 chunk cols [cc*128, +128), wave slice = 32 cols
        f32x4 c0[4][2];
        #pragma unroll
        for (int mt = 0; mt < 4; ++mt) { c0[mt][0] = zero4; c0[mt][1] = zero4; }
        #pragma unroll
        for (int ks = 0; ks < 4; ++ks) {
            half8 Ah[4], Al[4];
            if (ks < 2) {
                #pragma unroll
                for (int mt = 0; mt < 4; ++mt) {
                    int m = wm * 64 + mt * 16 + (l & 15);
                    int gb = ks * 8 + (l >> 4) * 2;
                    const unsigned char* base = smem + m * 256;
                    u32x4 w0 = *(const u32x4*)(base + (((gb)     ^ (m & 7)) << 4));
                    u32x4 w1 = *(const u32x4*)(base + (((gb + 1) ^ (m & 7)) << 4));
                    unpackA(w0, w1, Ah[mt], Al[mt]);
                }
            } else {
                #pragma unroll
                for (int mt = 0; mt < 4; ++mt) {
                    int off = (mt * 2 + (ks - 2)) * 512 + l * 8;
                    Ah[mt] = *(const half8*)(embAh + off);
                    Al[mt] = *(const half8*)(embAl + off);
                }
            }
            #pragma unroll
            for (int nt2 = 0; nt2 < 2; ++nt2) {
                int ntg = cc * 8 + wn * 2 + nt2;
                long boff = (long)((ks * 32 + ntg) * 64 + l) * 8;
                half8 Bh = *(const half8*)(fw0h + boff);
                half8 Bl = *(const half8*)(fw0l + boff);
                #pragma unroll
                for (int mt = 0; mt < 4; ++mt) {
                    c0[mt][nt2] = MFMA16(Ah[mt], Bh, c0[mt][nt2]);
                    c0[mt][nt2] = MFMA16(Ah[mt], Bl, c0[mt][nt2]);
                    c0[mt][nt2] = MFMA16(Al[mt], Bh, c0[mt][nt2]);
                }
            }
        }
        __syncthreads();   // prev layer1 done reading h0chunk
        // epilogue: +fb0, leaky, split-pack -> h0chunk
        #pragma unroll
        for (int mt = 0; mt < 4; ++mt)
        #pragma unroll
        for (int nt2 = 0; nt2 < 2; ++nt2) {
            int klocal = wn * 32 + nt2 * 16 + (l & 15);
            float bias = fb0[cc * 128 + klocal];
            #pragma unroll
            for (int r = 0; r < 4; ++r) {
                int m = wm * 64 + mt * 16 + (l >> 4) * 4 + r;
                float v = leaky(c0[mt][nt2][r] + bias);
                *(uint32_t*)(smem + 32768 + m * 512 +
                             (((klocal >> 2) ^ (m & 7)) << 4) + (klocal & 3) * 4)
                    = packsplit(v);
            }
        }
        __syncthreads();
        // layer1 partial: K-chunk cc (128 cols of h0)
        #pragma unroll
        for (int ks = 0; ks < 4; ++ks) {
            half8 Ah[4], Al[4];
            #pragma unroll
            for (int mt = 0; mt < 4; ++mt) {
                int m = wm * 64 + mt * 16 + (l & 15);
                int gb = ks * 8 + (l >> 4) * 2;
                const unsigned char* base = smem + 32768 + m * 512;
                u32x4 w0 = *(const u32x4*)(base + (((gb)     ^ (m & 7)) << 4));
                u32x4 w1 = *(const u32x4*)(base + (((gb + 1) ^ (m & 7)) << 4));
                unpackA(w0, w1, Ah[mt], Al[mt]);
            }
            #pragma unroll
            for (int nt = 0; nt < 8; ++nt) {
                int ntg = wn * 8 + nt;
                long boff = (long)(((cc * 4 + ks) * 32 + ntg) * 64 + l) * 8;
                half8 Bh = *(const half8*)(fw1h + boff);
                half8 Bl = *(const half8*)(fw1l + boff);
                #pragma unroll
                for (int mt = 0; mt < 4; ++mt) {
                    acc1[mt][nt] = MFMA16(Ah[mt], Bh, acc1[mt][nt]);
                    acc1[mt][nt] = MFMA16(Ah[mt], Bl, acc1[mt][nt]);
                    acc1[mt][nt] = MFMA16(Al[mt], Bh, acc1[mt][nt]);
                }
            }
        }
    }

    // h1 = leaky(acc1 + fb1)
    #pragma unroll
    for (int mt = 0; mt < 4; ++mt)
        #pragma unroll
        for (int nt = 0; nt < 8; ++nt) {
            float bias = fb1[wn * 128 + nt * 16 + (l & 15)];
            #pragma unroll
            for (int r = 0; r < 4; ++r)
                acc1[mt][nt][r] = leaky(acc1[mt][nt][r] + bias);
        }

    // layer2 in 4 quarters of 32 rows through LDS
    float* h1buf = (float*)smem;
    const int r32 = t >> 4;          // 0..31
    const int sub = t & 15;
    #pragma unroll
    for (int q = 0; q < 4; ++q) {
        __syncthreads();             // prior h0chunk/h1buf reads complete
        if (wm == (q >> 1)) {
            #pragma unroll
            for (int mt2 = 0; mt2 < 2; ++mt2) {
                int mtq = (q & 1) * 2 + mt2;
                #pragma unroll
                for (int nt = 0; nt < 8; ++nt) {
                    int col = wn * 128 + nt * 16 + (l & 15);
                    #pragma unroll
                    for (int r = 0; r < 4; ++r) {
                        int rowq = mt2 * 16 + (l >> 4) * 4 + r;
                        h1buf[rowq * 520 + col] = acc1[mtq][nt][r];
                    }
                }
            }
        }
        __syncthreads();
        int grow = tile * 128 + q * 32 + r32;
        int node = grow & 63;
        const float* w2a = w2T + (2 * node) * 512;
        const float* w2b = w2a + 512;
        const float* hr  = h1buf + r32 * 520;
        float s0 = 0.f, s1 = 0.f;
        #pragma unroll
        for (int u = 0; u < 8; ++u) {
            int a = sub * 4 + u * 64;
            float4 h4 = *(const float4*)(hr + a);
            float4 wa = *(const float4*)(w2a + a);
            float4 wb = *(const float4*)(w2b + a);
            s0 = fmaf(h4.x, wa.x, s0); s0 = fmaf(h4.y, wa.y, s0);
            s0 = fmaf(h4.z, wa.z, s0); s0 = fmaf(h4.w, wa.w, s0);
            s1 = fmaf(h4.x, wb.x, s1); s1 = fmaf(h4.y, wb.y, s1);
            s1 = fmaf(h4.z, wb.z, s1); s1 = fmaf(h4.w, wb.w, s1);
        }
        s0 += __shfl_xor(s0, 1, 64); s0 += __shfl_xor(s0, 2, 64);
        s0 += __shfl_xor(s0, 4, 64); s0 += __shfl_xor(s0, 8, 64);
        s1 += __shfl_xor(s1, 1, 64); s1 += __shfl_xor(s1, 2, 64);
        s1 += __shfl_xor(s1, 4, 64); s1 += __shfl_xor(s1, 8, 64);
        if (sub == 0) {
            int o = (grow >> 6) * 128 + 2 * node;
            out[o]     = s0 + fb2[2 * node];
            out[o + 1] = s1 + fb2[2 * node + 1];
        }
    }
}

// ---------------- launch ----------------

extern "C" void kernel_launch(void* const* d_in, const int* in_sizes, int n_in,
                              void* d_out, int out_size, void* d_ws, size_t ws_size,
                              hipStream_t stream)
{
    const float* samples    = (const float*)d_in[0];
    const float* graphs     = (const float*)d_in[1];
    const float* embeddings = (const float*)d_in[3];
    const float* w          = (const float*)d_in[4];
    const float* g_w0 = (const float*)d_in[5];
    const float* g_b0 = (const float*)d_in[6];
    const float* g_w1 = (const float*)d_in[7];
    const float* g_b1 = (const float*)d_in[8];
    const float* g_w2 = (const float*)d_in[9];
    const float* g_b2 = (const float*)d_in[10];
    const float* f_w0 = (const float*)d_in[11];
    const float* f_b0 = (const float*)d_in[12];
    const float* f_w1 = (const float*)d_in[13];
    const float* f_b1 = (const float*)d_in[14];
    const float* f_w2 = (const float*)d_in[15];
    const float* f_b2 = (const float*)d_in[16];
    float* out = (float*)d_out;

    float* ws     = (float*)d_ws;
    float* base_g = ws;               // 64*512
    float* base_f = ws + 32768;       // 64*512 (unused by k_f, kept)
    float* w2T    = ws + 65536;       // 128*512
    float* emb_s  = ws + 131072;      // 256*64*64
    _Float16* f16base = (_Float16*)(ws + 1179648);
    _Float16* fw1h  = f16base;               // 262144
    _Float16* fw1l  = f16base + 262144;      // 262144
    _Float16* fw0h  = f16base + 524288;      // 65536
    _Float16* fw0l  = f16base + 589824;      // 65536
    _Float16* embAh = f16base + 655360;      // 4096
    _Float16* embAl = f16base + 659456;      // 4096

    hipLaunchKernelGGL(k_base, dim3(256), dim3(256), 0, stream,
                       embeddings, g_w0, g_b0, f_w0, f_b0, base_g, base_f);
    hipLaunchKernelGGL(k_w2t, dim3(256), dim3(256), 0, stream, f_w2, w2T);
    hipLaunchKernelGGL(k_splitw, dim3(162), dim3(256), 0, stream,
                       f_w0, f_w1, embeddings,
                       fw0h, fw0l, fw1h, fw1l, embAh, embAl);
    hipLaunchKernelGGL(k_embs, dim3(1024), dim3(256), 0, stream,
                       samples, g_w0, g_w1, g_b1, g_w2, g_b2, base_g, emb_s);
    hipLaunchKernelGGL(k_f, dim3(1024), dim3(512), 0, stream,
                       graphs, w, emb_s, f_b0, f_b1, w2T, f_b2,
                       fw0h, fw0l, fw1h, fw1l, embAh, embAl, out);
}